// Round 7
// baseline (364.837 us; speedup 1.0000x reference)
//
#include <hip/hip_runtime.h>
#include <math.h>

// ---------------------------------------------------------------------------
// HierarchicalVAE, MI355X (gfx950), fp32 — R13: single kernel, light MALL
// barriers, FULL per-stage occupancy.
// R12 post-mortem: mechanism validated (absmax exactly = R7's; coherence via
// agent-scope stores + first-touch-post-barrier cached reads works), but
// 256x512 = 2 waves/SIMD halved R7's stage occupancy and ran the two chunks
// of 512-chunk stages serially -> phases 19us vs R7's 13us stage+boundary.
// R13: 256 blocks x 1024 threads (1/CU co-resident, 4 waves/SIMD). The two
// chunks of each 512-chunk stage run IN PARALLEL as two 512-thread groups
// (tg = tid>>9) with per-tg LDS scratch — R7-identical numerics per chunk.
// Small stages (mulv/heads/ref2) keep R7 mapping with tg1 idle; raster uses
// all 1024 threads. 1 launch + 8 light barriers replaces 9 launches.
//
// Output layout (flat f32): rendered@0, mu@100352, logvar@108544,
// cp@116736, widths@124928, alphas@125184.
// ---------------------------------------------------------------------------

#define O_MU  100352
#define O_LV  108544
#define O_CP  116736
#define O_WD  124928
#define O_AL  125184

// workspace float offsets
#define W_H1   0        // h1_T  [256][128]
#define W_HE   32768    // he_T  [256][128]
#define W_MUT  65536    // mu_T  [64][128]
#define W_LVT  73728    // lv_T  [64][128]
#define W_D1   81920    // d1_T  [512][128]
#define W_H2   147456   // h2_T  [512][128]
#define W_PN   212992   // pn_T  [28][128]
#define W_R1   216576   // r1_T  [512][128]
#define W_PT   282112   // P_T   [52][128]
#define W_WA   288768   // wa_T  [4][128]
#define W_BAR  289280   // 8 unsigned barrier counters
#define NBLK   256

__device__ __forceinline__ float leaky(float x) { return x >= 0.f ? x : 0.2f * x; }
__device__ __forceinline__ float seluf(float x) {
    const float s = 1.0507009873554805f, a = 1.6732632423543772f;
    return x > 0.f ? s * x : s * (a * expm1f(x));
}
__device__ __forceinline__ float sigm(float x) { return 1.f / (1.f + expf(-x)); }

// agent-scope (device-coherent, MALL) store for cross-block activations
__device__ __forceinline__ void stws(float* p, float v) {
    __hip_atomic_store(p, v, __ATOMIC_RELAXED, __HIP_MEMORY_SCOPE_AGENT);
}

// light phase barrier (validated R12): vmcnt(0) before s_barrier drains all
// waves' sc1 stores; tid0 arrives and spins at MALL; timeout escape = no hang.
__device__ __forceinline__ void arrive_wait(unsigned* c) {
    __syncthreads();
    if (threadIdx.x == 0) {
        __hip_atomic_fetch_add(c, 1u, __ATOMIC_RELAXED, __HIP_MEMORY_SCOPE_AGENT);
        unsigned tries = 0;
        while (__hip_atomic_load(c, __ATOMIC_RELAXED, __HIP_MEMORY_SCOPE_AGENT) < NBLK) {
            __builtin_amdgcn_s_sleep(4);
            if (++tries > (1u << 16)) break;   // safety escape, never hang
        }
    }
    __syncthreads();
    asm volatile("" ::: "memory");   // keep post-barrier loads below the wait
}

__global__ __launch_bounds__(1024, 4)
void vae_flow2(const float* __restrict__ x, const float* __restrict__ eps,
               const float* __restrict__ enc_w1, const float* __restrict__ enc_b1,
               const float* __restrict__ enc_w2, const float* __restrict__ enc_b2,
               const float* __restrict__ mu_w, const float* __restrict__ mu_b,
               const float* __restrict__ lv_w, const float* __restrict__ lv_b,
               const float* __restrict__ dec_w1, const float* __restrict__ dec_b1,
               const float* __restrict__ dec_w2, const float* __restrict__ dec_b2,
               const float* __restrict__ cp_w, const float* __restrict__ cp_b,
               const float* __restrict__ ref_w1, const float* __restrict__ ref_b1,
               const float* __restrict__ ref_w2, const float* __restrict__ ref_b2,
               const float* __restrict__ wd_w, const float* __restrict__ wd_b,
               const float* __restrict__ al_w, const float* __restrict__ al_b,
               float* __restrict__ out, float* __restrict__ ws) {
    __shared__ float sPart[2048];   // 2 tg x 1024 reduce scratch (8 KB)
    __shared__ float sP[56];
    __shared__ float sWA[4];
    __shared__ float sQ[128];

    const int b   = blockIdx.x;
    const int tid = threadIdx.x;        // 0..1023
    const int tg  = tid >> 9;           // parallel chunk-half 0/1
    const int t5  = tid & 511;          // R7-kernel-local tid
    const int lane = t5 & 63, ks = t5 >> 6;
    float* const sp = sPart + tg * 1024;

    float* const h1T = ws + W_H1;
    float* const heT = ws + W_HE;
    float* const muT = ws + W_MUT;
    float* const lvT = ws + W_LVT;
    float* const d1T = ws + W_D1;
    float* const h2T = ws + W_H2;
    float* const pnT = ws + W_PN;
    float* const r1T = ws + W_R1;
    float* const PT  = ws + W_PT;
    float* const waT = ws + W_WA;
    unsigned* const bar = (unsigned*)(ws + W_BAR);

    // ====== stage 1: enc1 — 512 chunks, both tgs in parallel (slice 98) =======
    {
        const int c = b + 256 * tg;
        const int j = c >> 1, h = c & 1;
        const int r = h * 64 + lane;
        const float* __restrict__ xr = x + r * 784;
        const int k0 = ks * 98;
        float acc = 0.f;
#pragma unroll 7
        for (int i = 0; i < 98; i++)
            acc = fmaf(xr[k0 + i], enc_w1[(k0 + i) * 256 + j], acc);
        sp[ks * 64 + lane] = acc;
        __syncthreads();
        if (t5 < 64) {
            float s = enc_b1[j];
#pragma unroll
            for (int q = 0; q < 8; q++) s += sp[q * 64 + t5];
            stws(h1T + j * 128 + h * 64 + t5, leaky(s));
        }
    }
    arrive_wait(bar + 0);

    // ====== stage 2: enc2 — 512 chunks, both tgs (slice 32) ====================
    {
        const int c = b + 256 * tg;
        const int j = c >> 1, h = c & 1;
        const int r = h * 64 + lane;
        const int k0 = ks * 32;
        float acc = 0.f;
#pragma unroll 8
        for (int i = 0; i < 32; i++)
            acc = fmaf(h1T[(k0 + i) * 128 + r], enc_w2[(k0 + i) * 256 + j], acc);
        sp[ks * 64 + lane] = acc;
        __syncthreads();
        if (t5 < 64) {
            float s = enc_b2[j];
#pragma unroll
            for (int q = 0; q < 8; q++) s += sp[q * 64 + t5];
            stws(heT + j * 128 + h * 64 + t5, leaky(s));
        }
    }
    arrive_wait(bar + 1);

    // ====== stage 3: mu|lv — 256 chunks (tg0 only; R7 mapping) =================
    {
        const int meta = b >> 1, h = b & 1;
        const int head = meta >> 6, col = meta & 63;
        const float* __restrict__ w = head ? lv_w : mu_w;
        const int r = h * 64 + lane;
        const int k0 = ks * 32;
        if (tg == 0) {
            float acc = 0.f;
#pragma unroll 8
            for (int i = 0; i < 32; i++)
                acc = fmaf(heT[(k0 + i) * 128 + r], w[(k0 + i) * 64 + col], acc);
            sPart[ks * 64 + lane] = acc;
        }
        __syncthreads();
        if (tid < 64) {
            float s = (head ? lv_b : mu_b)[col];
#pragma unroll
            for (int q = 0; q < 8; q++) s += sPart[q * 64 + tid];
            const int rr = h * 64 + tid;
            stws((head ? lvT : muT) + col * 128 + rr, s);
            out[(head ? O_LV : O_MU) + rr * 64 + col] = s;
        }
    }
    arrive_wait(bar + 2);

    // ====== stage 4: dec1 — 512 chunks, both tgs (2 cols, slice 8) =============
    {
        const int c = b + 256 * tg;
        const int j0 = (c >> 1) * 2, h = c & 1;
        const int r = h * 64 + lane;
        const int k0 = ks * 8;
        float a0 = 0.f, a1 = 0.f;
#pragma unroll
        for (int i = 0; i < 8; i++) {
            const int k = k0 + i;
            float zv = fmaf(eps[r * 64 + k], expf(0.5f * lvT[k * 128 + r]), muT[k * 128 + r]);
            a0 = fmaf(zv, dec_w1[k * 512 + j0],     a0);
            a1 = fmaf(zv, dec_w1[k * 512 + j0 + 1], a1);
        }
        sp[ks * 128 + lane] = a0; sp[ks * 128 + 64 + lane] = a1;
        __syncthreads();
        if (t5 < 128) {
            const int ci = t5 >> 6, ll = t5 & 63;
            float s = dec_b1[j0 + ci];
#pragma unroll
            for (int q = 0; q < 8; q++) s += sp[q * 128 + ci * 64 + ll];
            stws(d1T + (j0 + ci) * 128 + h * 64 + ll, seluf(s));
        }
    }
    arrive_wait(bar + 3);

    // ====== stage 5: dec2 — 512 chunks, both tgs (2 cols, slice 64) ============
    {
        const int c = b + 256 * tg;
        const int j0 = (c >> 1) * 2, h = c & 1;
        const int r = h * 64 + lane;
        const int k0 = ks * 64;
        float a0 = 0.f, a1 = 0.f;
#pragma unroll 4
        for (int i = 0; i < 64; i++) {
            const float v = d1T[(k0 + i) * 128 + r];
            a0 = fmaf(v, dec_w2[(k0 + i) * 512 + j0],     a0);
            a1 = fmaf(v, dec_w2[(k0 + i) * 512 + j0 + 1], a1);
        }
        sp[ks * 128 + lane] = a0; sp[ks * 128 + 64 + lane] = a1;
        __syncthreads();
        if (t5 < 128) {
            const int ci = t5 >> 6, ll = t5 & 63;
            float s = dec_b2[j0 + ci];
#pragma unroll
            for (int q = 0; q < 8; q++) s += sp[q * 128 + ci * 64 + ll];
            stws(h2T + (j0 + ci) * 128 + h * 64 + ll, seluf(s));
        }
    }
    arrive_wait(bar + 4);

    // ====== stage 6: heads — 64 chunks (c<64; R7 mapping) ======================
    {
        const int c = b + 256 * tg;
        if (c < 64) {
            const int j = c >> 1, h = c & 1;
            const float* __restrict__ w; int ldw, col;
            if (j < 28)      { w = cp_w; ldw = 28; col = j; }
            else if (j < 30) { w = wd_w; ldw = 2;  col = j - 28; }
            else             { w = al_w; ldw = 2;  col = j - 30; }
            const int r = h * 64 + lane;
            const int k0 = ks * 64;
            float acc = 0.f;
#pragma unroll 8
            for (int i = 0; i < 64; i++)
                acc = fmaf(h2T[(k0 + i) * 128 + r], w[(k0 + i) * ldw + col], acc);
            sp[ks * 64 + lane] = acc;
        }
        __syncthreads();
        if (t5 < 64 && (b + 256 * tg) < 64) {
            const int c2 = b + 256 * tg;
            const int j = c2 >> 1, h = c2 & 1;
            float s = 0.f;
#pragma unroll
            for (int q = 0; q < 8; q++) s += sp[q * 64 + t5];
            const int rr = h * 64 + t5;
            if (j < 28) {
                stws(pnT + j * 128 + rr, tanhf(s + cp_b[j]));
            } else if (j < 30) {
                const int col = j - 28;
                float v = fmaf(sigm(s + wd_b[col]), 2.f, 1.f);
                out[O_WD + rr * 2 + col] = v; stws(waT + col * 128 + rr, v);
            } else {
                const int col = j - 30;
                float v = sigm(s + al_b[col]);
                out[O_AL + rr * 2 + col] = v; stws(waT + (2 + col) * 128 + rr, v);
            }
        }
    }
    arrive_wait(bar + 5);

    // ====== stage 7: ref1 — 512 chunks, both tgs (2 cols, slice 12, k<92) ======
    {
        const int c = b + 256 * tg;
        const int j0 = (c >> 1) * 2, h = c & 1;
        const int r = h * 64 + lane;
        float a0 = 0.f, a1 = 0.f;
#pragma unroll
        for (int i = 0; i < 12; i++) {
            const int k = ks * 12 + i;
            if (k < 92) {
                float v = (k < 64)
                    ? fmaf(eps[r * 64 + k], expf(0.5f * lvT[k * 128 + r]), muT[k * 128 + r])
                    : pnT[(k - 64) * 128 + r];
                a0 = fmaf(v, ref_w1[k * 512 + j0],     a0);
                a1 = fmaf(v, ref_w1[k * 512 + j0 + 1], a1);
            }
        }
        sp[ks * 128 + lane] = a0; sp[ks * 128 + 64 + lane] = a1;
        __syncthreads();
        if (t5 < 128) {
            const int ci = t5 >> 6, ll = t5 & 63;
            float s = ref_b1[j0 + ci];
#pragma unroll
            for (int q = 0; q < 8; q++) s += sp[q * 128 + ci * 64 + ll];
            stws(r1T + (j0 + ci) * 128 + h * 64 + ll, seluf(s));
        }
    }
    arrive_wait(bar + 6);

    // ====== stage 8: ref2 — 104 chunks (c<104; R7 mapping) =====================
    {
        const int c = b + 256 * tg;
        if (c < 104) {
            const int j = c >> 1, h = c & 1;
            const int r = h * 64 + lane;
            const int k0 = ks * 64;
            float acc = 0.f;
#pragma unroll 8
            for (int i = 0; i < 64; i++)
                acc = fmaf(r1T[(k0 + i) * 128 + r], ref_w2[(k0 + i) * 52 + j], acc);
            sp[ks * 64 + lane] = acc;
        }
        __syncthreads();
        if (t5 < 64 && (b + 256 * tg) < 104) {
            const int c2 = b + 256 * tg;
            const int j = c2 >> 1, h = c2 & 1;
            float s = ref_b2[j];
#pragma unroll
            for (int q = 0; q < 8; q++) s += sp[q * 64 + t5];
            stws(PT + j * 128 + h * 64 + t5, fmaf(tanhf(s), 12.f, 14.f));
        }
    }
    arrive_wait(bar + 7);

    // ====== stage 9: raster — 256 chunks, all 1024 threads =====================
    {
        const int row = b >> 1, half = b & 1;
        if (tid < 52) sP[tid] = PT[tid * 128 + row];
        if (tid >= 64 && tid < 68) sWA[tid - 64] = waT[(tid - 64) * 128 + row];
        __syncthreads();
        if (half == 0 && tid < 64) {
            const int idx = tid, p = idx >> 5, rest = idx & 31;
            const int s = rest >> 3, kk = (rest >> 1) & 3, d = idx & 1;
            out[O_CP + row * 64 + idx] = sP[p * 26 + (3 * s + kk) * 2 + d];
        }
        if (tid < 128) {
            const int idx = tid, p = idx >> 6, s = (idx >> 4) & 3, ti = (idx >> 1) & 7, d = idx & 1;
            const float t = (float)ti / 7.0f, mt = 1.0f - t;
            const float c0 = mt * mt * mt, c1 = 3.f * mt * mt * t;
            const float c2 = 3.f * mt * t * t, c3 = t * t * t;
            const float* base = sP + p * 26 + 6 * s + d;
            sQ[idx] = c0 * base[0] + c1 * base[2] + c2 * base[4] + c3 * base[6];
        }
        __syncthreads();
        const float2* __restrict__ sQ2 = (const float2*)sQ;
        for (int u = tid; u < 1568; u += 1024) {
            const int pixel = half * 392 + (u >> 2);
            const int sub = u & 3;
            const int py = pixel / 28, px = pixel - py * 28;
            const float sy = ((float)(2 * py + (sub >> 1)) + 0.5f) * 0.5f;
            const float sx = ((float)(2 * px + (sub & 1)) + 0.5f) * 0.5f;
            float img = 1.0f;
#pragma unroll
            for (int p = 0; p < 2; p++) {
                float dmin2 = 1e30f;
                int cnt = 0;
                float2 cur = sQ2[p * 32];
                bool bp = cur.y > sy;
#pragma unroll
                for (int m = 0; m < 32; m++) {
                    float2 nxt = sQ2[p * 32 + ((m + 1) & 31)];
                    float dx = sx - cur.x;
                    float dy = sy - cur.y;
                    dmin2 = fminf(dmin2, fmaf(dx, dx, dy * dy));
                    bool bn = nxt.y > sy;
                    float den = nxt.y - cur.y + 1e-8f;
                    float lhs = dx * den;
                    float rhs = dy * (nxt.x - cur.x);
                    if ((bp != bn) && ((lhs < rhs) == (den > 0.0f))) cnt++;
                    cur = nxt;
                    bp = bn;
                }
                float dist = sqrtf(dmin2);
                float stroke = fminf(fmaxf(fmaf(sWA[p], 0.5f, 0.5f) - dist, 0.f), 1.f);
                float cov = fmaxf((float)(cnt & 1), stroke);
                img *= fmaf(-sWA[2 + p], cov, 1.0f);
            }
            img += __shfl_xor(img, 1);
            img += __shfl_xor(img, 2);
            if (sub == 0) out[row * 784 + pixel] = 1.0f - 0.25f * img;
        }
    }
}

extern "C" void kernel_launch(void* const* d_in, const int* in_sizes, int n_in,
                              void* d_out, int out_size, void* d_ws, size_t ws_size,
                              hipStream_t stream) {
    const float* x      = (const float*)d_in[0];
    const float* eps    = (const float*)d_in[1];
    const float* enc_w1 = (const float*)d_in[2];
    const float* enc_b1 = (const float*)d_in[3];
    const float* enc_w2 = (const float*)d_in[4];
    const float* enc_b2 = (const float*)d_in[5];
    const float* mu_w   = (const float*)d_in[6];
    const float* mu_b   = (const float*)d_in[7];
    const float* lv_w   = (const float*)d_in[8];
    const float* lv_b   = (const float*)d_in[9];
    const float* dec_w1 = (const float*)d_in[10];
    const float* dec_b1 = (const float*)d_in[11];
    const float* dec_w2 = (const float*)d_in[12];
    const float* dec_b2 = (const float*)d_in[13];
    const float* cp_w   = (const float*)d_in[14];
    const float* cp_b   = (const float*)d_in[15];
    const float* ref_w1 = (const float*)d_in[16];
    const float* ref_b1 = (const float*)d_in[17];
    const float* ref_w2 = (const float*)d_in[18];
    const float* ref_b2 = (const float*)d_in[19];
    const float* wd_w   = (const float*)d_in[20];
    const float* wd_b   = (const float*)d_in[21];
    const float* al_w   = (const float*)d_in[22];
    const float* al_b   = (const float*)d_in[23];

    float* out = (float*)d_out;
    float* ws  = (float*)d_ws;   // needs 289312 floats ≈ 1.16 MB

    // zero the 8 barrier counters (ws is re-poisoned between iterations)
    hipMemsetAsync(ws + W_BAR, 0, 8 * sizeof(unsigned), stream);

    vae_flow2<<<256, 1024, 0, stream>>>(x, eps, enc_w1, enc_b1, enc_w2, enc_b2,
                                        mu_w, mu_b, lv_w, lv_b, dec_w1, dec_b1,
                                        dec_w2, dec_b2, cp_w, cp_b, ref_w1, ref_b1,
                                        ref_w2, ref_b2, wd_w, wd_b, al_w, al_b,
                                        out, ws);
}

// Round 9
// 211.074 us; speedup vs baseline: 1.7285x; 1.7285x over previous
//
#include <hip/hip_runtime.h>
#include <math.h>

// ---------------------------------------------------------------------------
// HierarchicalVAE, MI355X (gfx950), fp32 — R15: R12 config + ILP-merged
// chunks + two-level barrier.
// R14 post-mortem: 512 blocks x 512 thr is NOT guaranteed co-resident
// (2 blocks/CU at the exact VGPR limit); barrier timeout escape turned the
// resulting stall into silent wrong answers (absmax 0.98). Hard rule:
// in-kernel barriers only at <=256 blocks x 512 thr (R10/R12-proven).
// R15: 256x512 (validated co-residency + MALL-store coherence, absmax==R7).
// Fix R12's measured deficiency — serial dual chunks — by ILP merge: chunk
// pair (c, c+256) shares h, r and the whole activation-load stream; one loop
// with 2x/4x accumulators doubles weight-load MLP and halves the serial
// latency chain. Numerics per output column identical to R7 (same K-slice,
// same 8-term reduce order). Barrier: 8 padded group counters (32 arrivals
// each) + block0 gather + read-only release flag (removes 256-RMW line
// contention). Timeout escape retained but dormant in this proven regime.
//
// Output layout (flat f32): rendered@0, mu@100352, logvar@108544,
// cp@116736, widths@124928, alphas@125184.
// ---------------------------------------------------------------------------

#define O_MU  100352
#define O_LV  108544
#define O_CP  116736
#define O_WD  124928
#define O_AL  125184

// workspace float offsets
#define W_H1   0        // h1_T  [256][128]
#define W_HE   32768    // he_T  [256][128]
#define W_MUT  65536    // mu_T  [64][128]
#define W_LVT  73728    // lv_T  [64][128]
#define W_D1   81920    // d1_T  [512][128]
#define W_H2   147456   // h2_T  [512][128]
#define W_PN   212992   // pn_T  [28][128]
#define W_R1   216576   // r1_T  [512][128]
#define W_PT   282112   // P_T   [52][128]
#define W_WA   288768   // wa_T  [4][128]
#define W_SYNC 289280   // 8 x (8 groups x 16) counters + 8 x 16 flags = 1152 u32
#define NBLK   256
#define NGRP   8
#define GQ     32       // blocks per arrival group

__device__ __forceinline__ float leaky(float x) { return x >= 0.f ? x : 0.2f * x; }
__device__ __forceinline__ float seluf(float x) {
    const float s = 1.0507009873554805f, a = 1.6732632423543772f;
    return x > 0.f ? s * x : s * (a * expm1f(x));
}
__device__ __forceinline__ float sigm(float x) { return 1.f / (1.f + expf(-x)); }

// agent-scope (device-coherent, MALL) store for cross-block activations
__device__ __forceinline__ void stws(float* p, float v) {
    __hip_atomic_store(p, v, __ATOMIC_RELAXED, __HIP_MEMORY_SCOPE_AGENT);
}
__device__ __forceinline__ unsigned ldu(const unsigned* p) {
    return __hip_atomic_load(p, __ATOMIC_RELAXED, __HIP_MEMORY_SCOPE_AGENT);
}

// two-level light barrier (256 blocks, proven co-resident regime).
// __syncthreads drains vmcnt (stws stores at MALL) before tid0 arrives.
__device__ __forceinline__ void gbar(unsigned* sync, int bi, int b) {
    __syncthreads();
    if (threadIdx.x == 0) {
        unsigned* cnt  = sync + bi * (NGRP * 16) + (b & (NGRP - 1)) * 16;
        unsigned* flag = sync + 8 * (NGRP * 16) + bi * 16;
        __hip_atomic_fetch_add(cnt, 1u, __ATOMIC_RELAXED, __HIP_MEMORY_SCOPE_AGENT);
        unsigned tries = 0;
        if (b == 0) {
            int g = 0;
            while (g < NGRP) {
                if (ldu(sync + bi * (NGRP * 16) + g * 16) >= GQ) { ++g; continue; }
                __builtin_amdgcn_s_sleep(2);
                if (++tries > (1u << 20)) break;
            }
            __hip_atomic_store(flag, 1u, __ATOMIC_RELAXED, __HIP_MEMORY_SCOPE_AGENT);
        } else {
            while (!ldu(flag)) {
                __builtin_amdgcn_s_sleep(2);
                if (++tries > (1u << 20)) break;
            }
        }
    }
    __syncthreads();
    asm volatile("" ::: "memory");   // keep post-barrier loads below the wait
}

__global__ __launch_bounds__(512)
void vae_flow4(const float* __restrict__ x, const float* __restrict__ eps,
               const float* __restrict__ enc_w1, const float* __restrict__ enc_b1,
               const float* __restrict__ enc_w2, const float* __restrict__ enc_b2,
               const float* __restrict__ mu_w, const float* __restrict__ mu_b,
               const float* __restrict__ lv_w, const float* __restrict__ lv_b,
               const float* __restrict__ dec_w1, const float* __restrict__ dec_b1,
               const float* __restrict__ dec_w2, const float* __restrict__ dec_b2,
               const float* __restrict__ cp_w, const float* __restrict__ cp_b,
               const float* __restrict__ ref_w1, const float* __restrict__ ref_b1,
               const float* __restrict__ ref_w2, const float* __restrict__ ref_b2,
               const float* __restrict__ wd_w, const float* __restrict__ wd_b,
               const float* __restrict__ al_w, const float* __restrict__ al_b,
               float* __restrict__ out, float* __restrict__ ws) {
    __shared__ float sPart[2048];   // 8 ks x 4 cols x 64 lanes (8 KB)
    __shared__ float sP[56];
    __shared__ float sWA[4];
    __shared__ float sQ[128];

    const int b   = blockIdx.x;
    const int tid = threadIdx.x;
    const int lane = tid & 63, ks = tid >> 6;
    const int h = b & 1;                 // row-half, shared by chunk pair
    const int r = h * 64 + lane;         // batch row for accumulation lanes

    float* const h1T = ws + W_H1;
    float* const heT = ws + W_HE;
    float* const muT = ws + W_MUT;
    float* const lvT = ws + W_LVT;
    float* const d1T = ws + W_D1;
    float* const h2T = ws + W_H2;
    float* const pnT = ws + W_PN;
    float* const r1T = ws + W_R1;
    float* const PT  = ws + W_PT;
    float* const waT = ws + W_WA;
    unsigned* const sync = (unsigned*)(ws + W_SYNC);

    // ====== stage 1: enc1 — cols j and j+128 merged (slice 98) ================
    {
        const int j = b >> 1;
        const float* __restrict__ xr = x + r * 784;
        const int k0 = ks * 98;
        float a0 = 0.f, a1 = 0.f;
#pragma unroll 7
        for (int i = 0; i < 98; i++) {
            const float xv = xr[k0 + i];
            a0 = fmaf(xv, enc_w1[(k0 + i) * 256 + j],       a0);
            a1 = fmaf(xv, enc_w1[(k0 + i) * 256 + j + 128], a1);
        }
        sPart[ks * 128 + lane] = a0;
        sPart[ks * 128 + 64 + lane] = a1;
        __syncthreads();
        if (tid < 128) {
            const int col = tid >> 6, ll = tid & 63;
            const int jc = (b >> 1) + col * 128;
            float s = enc_b1[jc];
#pragma unroll
            for (int q = 0; q < 8; q++) s += sPart[q * 128 + col * 64 + ll];
            stws(h1T + jc * 128 + h * 64 + ll, leaky(s));
        }
    }
    gbar(sync, 0, b);

    // ====== stage 2: enc2 — cols j and j+128 merged (slice 32) ================
    {
        const int j = b >> 1;
        const int k0 = ks * 32;
        float a0 = 0.f, a1 = 0.f;
#pragma unroll 8
        for (int i = 0; i < 32; i++) {
            const float v = h1T[(k0 + i) * 128 + r];
            a0 = fmaf(v, enc_w2[(k0 + i) * 256 + j],       a0);
            a1 = fmaf(v, enc_w2[(k0 + i) * 256 + j + 128], a1);
        }
        sPart[ks * 128 + lane] = a0;
        sPart[ks * 128 + 64 + lane] = a1;
        __syncthreads();
        if (tid < 128) {
            const int col = tid >> 6, ll = tid & 63;
            const int jc = (b >> 1) + col * 128;
            float s = enc_b2[jc];
#pragma unroll
            for (int q = 0; q < 8; q++) s += sPart[q * 128 + col * 64 + ll];
            stws(heT + jc * 128 + h * 64 + ll, leaky(s));
        }
    }
    gbar(sync, 1, b);

    // ====== stage 3: mu|lv — single chunk per block (R12-exact) ===============
    {
        const int meta = b >> 1;
        const int head = meta >> 6, col = meta & 63;
        const float* __restrict__ w = head ? lv_w : mu_w;
        const int k0 = ks * 32;
        float acc = 0.f;
#pragma unroll 8
        for (int i = 0; i < 32; i++)
            acc = fmaf(heT[(k0 + i) * 128 + r], w[(k0 + i) * 64 + col], acc);
        sPart[ks * 64 + lane] = acc;
        __syncthreads();
        if (tid < 64) {
            float s = (head ? lv_b : mu_b)[col];
#pragma unroll
            for (int q = 0; q < 8; q++) s += sPart[q * 64 + tid];
            const int rr = h * 64 + tid;
            stws((head ? lvT : muT) + col * 128 + rr, s);
            out[(head ? O_LV : O_MU) + rr * 64 + col] = s;
        }
    }
    gbar(sync, 2, b);

    // ====== stage 4: dec1 — col pairs j0,j0+1 and j0+256,j0+257 (slice 8) =====
    {
        const int j0 = (b >> 1) * 2;
        const int k0 = ks * 8;
        float a0 = 0.f, a1 = 0.f, a2 = 0.f, a3 = 0.f;
#pragma unroll
        for (int i = 0; i < 8; i++) {
            const int k = k0 + i;
            const float zv = fmaf(eps[r * 64 + k], expf(0.5f * lvT[k * 128 + r]),
                                  muT[k * 128 + r]);
            a0 = fmaf(zv, dec_w1[k * 512 + j0],       a0);
            a1 = fmaf(zv, dec_w1[k * 512 + j0 + 1],   a1);
            a2 = fmaf(zv, dec_w1[k * 512 + j0 + 256], a2);
            a3 = fmaf(zv, dec_w1[k * 512 + j0 + 257], a3);
        }
        sPart[ks * 256 + lane]       = a0;
        sPart[ks * 256 + 64 + lane]  = a1;
        sPart[ks * 256 + 128 + lane] = a2;
        sPart[ks * 256 + 192 + lane] = a3;
        __syncthreads();
        if (tid < 256) {
            const int col = tid >> 6, ll = tid & 63;
            const int jc = (b >> 1) * 2 + (col & 1) + (col >> 1) * 256;
            float s = dec_b1[jc];
#pragma unroll
            for (int q = 0; q < 8; q++) s += sPart[q * 256 + col * 64 + ll];
            stws(d1T + jc * 128 + h * 64 + ll, seluf(s));
        }
    }
    gbar(sync, 3, b);

    // ====== stage 5: dec2 — col pairs j0,j0+1 and j0+256,j0+257 (slice 64) ====
    {
        const int j0 = (b >> 1) * 2;
        const int k0 = ks * 64;
        float a0 = 0.f, a1 = 0.f, a2 = 0.f, a3 = 0.f;
#pragma unroll 4
        for (int i = 0; i < 64; i++) {
            const float v = d1T[(k0 + i) * 128 + r];
            a0 = fmaf(v, dec_w2[(k0 + i) * 512 + j0],       a0);
            a1 = fmaf(v, dec_w2[(k0 + i) * 512 + j0 + 1],   a1);
            a2 = fmaf(v, dec_w2[(k0 + i) * 512 + j0 + 256], a2);
            a3 = fmaf(v, dec_w2[(k0 + i) * 512 + j0 + 257], a3);
        }
        sPart[ks * 256 + lane]       = a0;
        sPart[ks * 256 + 64 + lane]  = a1;
        sPart[ks * 256 + 128 + lane] = a2;
        sPart[ks * 256 + 192 + lane] = a3;
        __syncthreads();
        if (tid < 256) {
            const int col = tid >> 6, ll = tid & 63;
            const int jc = (b >> 1) * 2 + (col & 1) + (col >> 1) * 256;
            float s = dec_b2[jc];
#pragma unroll
            for (int q = 0; q < 8; q++) s += sPart[q * 256 + col * 64 + ll];
            stws(h2T + jc * 128 + h * 64 + ll, seluf(s));
        }
    }
    gbar(sync, 4, b);

    // ====== stage 6: heads — 64 chunks (b<64, R12-exact) ======================
    if (b < 64) {
        const int j = b >> 1;
        const float* __restrict__ w; int ldw, col;
        if (j < 28)      { w = cp_w; ldw = 28; col = j; }
        else if (j < 30) { w = wd_w; ldw = 2;  col = j - 28; }
        else             { w = al_w; ldw = 2;  col = j - 30; }
        const int k0 = ks * 64;
        float acc = 0.f;
#pragma unroll 8
        for (int i = 0; i < 64; i++)
            acc = fmaf(h2T[(k0 + i) * 128 + r], w[(k0 + i) * ldw + col], acc);
        sPart[ks * 64 + lane] = acc;
        __syncthreads();
        if (tid < 64) {
            float s = 0.f;
#pragma unroll
            for (int q = 0; q < 8; q++) s += sPart[q * 64 + tid];
            const int rr = h * 64 + tid;
            if (j < 28) {
                stws(pnT + j * 128 + rr, tanhf(s + cp_b[col]));
            } else if (j < 30) {
                float v = fmaf(sigm(s + wd_b[col]), 2.f, 1.f);
                out[O_WD + rr * 2 + col] = v; stws(waT + col * 128 + rr, v);
            } else {
                float v = sigm(s + al_b[col]);
                out[O_AL + rr * 2 + col] = v; stws(waT + (2 + col) * 128 + rr, v);
            }
        }
    }
    gbar(sync, 5, b);

    // ====== stage 7: ref1 — col pairs merged (slice 12, guard k<92) ===========
    {
        const int j0 = (b >> 1) * 2;
        float a0 = 0.f, a1 = 0.f, a2 = 0.f, a3 = 0.f;
#pragma unroll
        for (int i = 0; i < 12; i++) {
            const int k = ks * 12 + i;
            if (k < 92) {
                const float v = (k < 64)
                    ? fmaf(eps[r * 64 + k], expf(0.5f * lvT[k * 128 + r]), muT[k * 128 + r])
                    : pnT[(k - 64) * 128 + r];
                a0 = fmaf(v, ref_w1[k * 512 + j0],       a0);
                a1 = fmaf(v, ref_w1[k * 512 + j0 + 1],   a1);
                a2 = fmaf(v, ref_w1[k * 512 + j0 + 256], a2);
                a3 = fmaf(v, ref_w1[k * 512 + j0 + 257], a3);
            }
        }
        sPart[ks * 256 + lane]       = a0;
        sPart[ks * 256 + 64 + lane]  = a1;
        sPart[ks * 256 + 128 + lane] = a2;
        sPart[ks * 256 + 192 + lane] = a3;
        __syncthreads();
        if (tid < 256) {
            const int col = tid >> 6, ll = tid & 63;
            const int jc = (b >> 1) * 2 + (col & 1) + (col >> 1) * 256;
            float s = ref_b1[jc];
#pragma unroll
            for (int q = 0; q < 8; q++) s += sPart[q * 256 + col * 64 + ll];
            stws(r1T + jc * 128 + h * 64 + ll, seluf(s));
        }
    }
    gbar(sync, 6, b);

    // ====== stage 8: ref2 — 104 chunks (b<104, R12-exact) =====================
    if (b < 104) {
        const int j = b >> 1;
        const int k0 = ks * 64;
        float acc = 0.f;
#pragma unroll 8
        for (int i = 0; i < 64; i++)
            acc = fmaf(r1T[(k0 + i) * 128 + r], ref_w2[(k0 + i) * 52 + j], acc);
        sPart[ks * 64 + lane] = acc;
        __syncthreads();
        if (tid < 64) {
            float s = ref_b2[j];
#pragma unroll
            for (int q = 0; q < 8; q++) s += sPart[q * 64 + tid];
            stws(PT + j * 128 + h * 64 + tid, fmaf(tanhf(s), 12.f, 14.f));
        }
    }
    gbar(sync, 7, b);

    // ====== stage 9: raster — row=b>>1, half=b&1 (R12-exact) ==================
    {
        const int row = b >> 1, half = b & 1;
        if (tid < 52) sP[tid] = PT[tid * 128 + row];
        if (tid >= 64 && tid < 68) sWA[tid - 64] = waT[(tid - 64) * 128 + row];
        __syncthreads();
        if (half == 0 && tid < 64) {
            const int idx = tid, p = idx >> 5, rest = idx & 31;
            const int s = rest >> 3, kk = (rest >> 1) & 3, d = idx & 1;
            out[O_CP + row * 64 + idx] = sP[p * 26 + (3 * s + kk) * 2 + d];
        }
        if (tid < 128) {
            const int idx = tid, p = idx >> 6, s = (idx >> 4) & 3, ti = (idx >> 1) & 7, d = idx & 1;
            const float t = (float)ti / 7.0f, mt = 1.0f - t;
            const float c0 = mt * mt * mt, c1 = 3.f * mt * mt * t;
            const float c2 = 3.f * mt * t * t, c3 = t * t * t;
            const float* base = sP + p * 26 + 6 * s + d;
            sQ[idx] = c0 * base[0] + c1 * base[2] + c2 * base[4] + c3 * base[6];
        }
        __syncthreads();
        const float2* __restrict__ sQ2 = (const float2*)sQ;
        for (int u = tid; u < 1568; u += 512) {
            const int pixel = half * 392 + (u >> 2);
            const int sub = u & 3;
            const int py = pixel / 28, px = pixel - py * 28;
            const float sy = ((float)(2 * py + (sub >> 1)) + 0.5f) * 0.5f;
            const float sx = ((float)(2 * px + (sub & 1)) + 0.5f) * 0.5f;
            float img = 1.0f;
#pragma unroll
            for (int p = 0; p < 2; p++) {
                float dmin2 = 1e30f;
                int cnt = 0;
                float2 cur = sQ2[p * 32];
                bool bp = cur.y > sy;
#pragma unroll
                for (int m = 0; m < 32; m++) {
                    float2 nxt = sQ2[p * 32 + ((m + 1) & 31)];
                    float dx = sx - cur.x;
                    float dy = sy - cur.y;
                    dmin2 = fminf(dmin2, fmaf(dx, dx, dy * dy));
                    bool bn = nxt.y > sy;
                    float den = nxt.y - cur.y + 1e-8f;
                    float lhs = dx * den;
                    float rhs = dy * (nxt.x - cur.x);
                    if ((bp != bn) && ((lhs < rhs) == (den > 0.0f))) cnt++;
                    cur = nxt;
                    bp = bn;
                }
                float dist = sqrtf(dmin2);
                float stroke = fminf(fmaxf(fmaf(sWA[p], 0.5f, 0.5f) - dist, 0.f), 1.f);
                float cov = fmaxf((float)(cnt & 1), stroke);
                img *= fmaf(-sWA[2 + p], cov, 1.0f);
            }
            img += __shfl_xor(img, 1);
            img += __shfl_xor(img, 2);
            if (sub == 0) out[row * 784 + pixel] = 1.0f - 0.25f * img;
        }
    }
}

extern "C" void kernel_launch(void* const* d_in, const int* in_sizes, int n_in,
                              void* d_out, int out_size, void* d_ws, size_t ws_size,
                              hipStream_t stream) {
    const float* x      = (const float*)d_in[0];
    const float* eps    = (const float*)d_in[1];
    const float* enc_w1 = (const float*)d_in[2];
    const float* enc_b1 = (const float*)d_in[3];
    const float* enc_w2 = (const float*)d_in[4];
    const float* enc_b2 = (const float*)d_in[5];
    const float* mu_w   = (const float*)d_in[6];
    const float* mu_b   = (const float*)d_in[7];
    const float* lv_w   = (const float*)d_in[8];
    const float* lv_b   = (const float*)d_in[9];
    const float* dec_w1 = (const float*)d_in[10];
    const float* dec_b1 = (const float*)d_in[11];
    const float* dec_w2 = (const float*)d_in[12];
    const float* dec_b2 = (const float*)d_in[13];
    const float* cp_w   = (const float*)d_in[14];
    const float* cp_b   = (const float*)d_in[15];
    const float* ref_w1 = (const float*)d_in[16];
    const float* ref_b1 = (const float*)d_in[17];
    const float* ref_w2 = (const float*)d_in[18];
    const float* ref_b2 = (const float*)d_in[19];
    const float* wd_w   = (const float*)d_in[20];
    const float* wd_b   = (const float*)d_in[21];
    const float* al_w   = (const float*)d_in[22];
    const float* al_b   = (const float*)d_in[23];

    float* out = (float*)d_out;
    float* ws  = (float*)d_ws;   // needs 290432 floats ≈ 1.16 MB

    // zero the sync area (8x8 padded counters + 8 flags = 1152 u32)
    hipMemsetAsync(ws + W_SYNC, 0, 1152 * sizeof(unsigned), stream);

    vae_flow4<<<256, 512, 0, stream>>>(x, eps, enc_w1, enc_b1, enc_w2, enc_b2,
                                       mu_w, mu_b, lv_w, lv_b, dec_w1, dec_b1,
                                       dec_w2, dec_b2, cp_w, cp_b, ref_w1, ref_b1,
                                       ref_w2, ref_b2, wd_w, wd_b, al_w, al_b,
                                       out, ws);
}